// Round 2
// baseline (457.303 us; speedup 1.0000x reference)
//
#include <hip/hip_runtime.h>
#include <cstdint>
#include <cstddef>

// ---------- types ----------
typedef __bf16 bf16;
typedef __bf16 bf16x8 __attribute__((ext_vector_type(8)));
typedef __bf16 bf16x4 __attribute__((ext_vector_type(4)));
typedef float  floatx4 __attribute__((ext_vector_type(4)));

typedef __attribute__((address_space(1))) void gvoid_t;
typedef __attribute__((address_space(3))) void lvoid_t;

#define MFMA16(a, b, c) __builtin_amdgcn_mfma_f32_16x16x32_bf16((a), (b), (c), 0, 0, 0)

// B=2, S=2048, D=1024, H=16, DH=64; tokens NT=4096; E3=3072
#define S_TOK 2048
#define E3 3072
#define DMODEL 1024

// ---------- fp32 -> bf16 convert ----------
__global__ __launch_bounds__(256) void cvt_f32_bf16(const float* __restrict__ s,
                                                    bf16* __restrict__ d, int n) {
  int i = (blockIdx.x * 256 + threadIdx.x) * 8;
  if (i >= n) return;
  const float4* p = (const float4*)(s + i);
  float4 a = p[0], b = p[1];
  bf16x8 o;
  o[0] = (bf16)a.x; o[1] = (bf16)a.y; o[2] = (bf16)a.z; o[3] = (bf16)a.w;
  o[4] = (bf16)b.x; o[5] = (bf16)b.y; o[6] = (bf16)b.z; o[7] = (bf16)b.w;
  *(bf16x8*)(d + i) = o;
}

// ---------- async global->LDS, 16B per lane ----------
__device__ __forceinline__ void gl_lds16(const bf16* g, bf16* l) {
  __builtin_amdgcn_global_load_lds((gvoid_t*)g, (lvoid_t*)l, 16, 0, 0);
}

// ---------- GEMM: C[m][n] = sum_k A[m][k] * Bt[n][k]  (m97 structure) ----------
// 128x128 tile, BK=32, 256 threads / 4 waves in 2x2, each wave 64x64 (4x4 MFMA tiles)
template <bool OUT_BF16>
__global__ __launch_bounds__(256) void gemm_bt(const bf16* __restrict__ A,
                                               const bf16* __restrict__ Bt,
                                               void* __restrict__ Cv,
                                               int M, int N, int K) {
  __shared__ bf16 sA[128 * 32];
  __shared__ bf16 sB[128 * 32];
  const int tid = threadIdx.x;
  const int wv = tid >> 6, lane = tid & 63;
  const int wr = wv >> 1, wc = wv & 1;
  const int lrow = lane & 15, lgrp = lane >> 4;
  const int R0 = blockIdx.y * 128, C0 = blockIdx.x * 128;

  floatx4 acc[4][4] = {};

  const bf16* gA = A + (size_t)(R0 + wv * 32 + (lane >> 2)) * K + (lane & 3) * 8;
  const bf16* gB = Bt + (size_t)(C0 + wv * 32 + (lane >> 2)) * K + (lane & 3) * 8;
  bf16* lA = sA + wv * 1024;  // wave-uniform LDS base; HW scatters lane i at +16B*i
  bf16* lB = sB + wv * 1024;
  const size_t rowstep = (size_t)16 * K;

  for (int k0 = 0; k0 < K; k0 += 32) {
    gl_lds16(gA + k0, lA);
    gl_lds16(gA + k0 + rowstep, lA + 512);
    gl_lds16(gB + k0, lB);
    gl_lds16(gB + k0 + rowstep, lB + 512);
    __syncthreads();  // drains vmcnt -> staged data visible
    bf16x8 af[4], bfr[4];
#pragma unroll
    for (int i = 0; i < 4; i++)
      af[i] = *(const bf16x8*)&sA[(wr * 64 + i * 16 + lrow) * 32 + lgrp * 8];
#pragma unroll
    for (int j = 0; j < 4; j++)
      bfr[j] = *(const bf16x8*)&sB[(wc * 64 + j * 16 + lrow) * 32 + lgrp * 8];
#pragma unroll
    for (int i = 0; i < 4; i++)
#pragma unroll
      for (int j = 0; j < 4; j++)
        acc[i][j] = MFMA16(af[i], bfr[j], acc[i][j]);
    __syncthreads();  // all waves done reading before restage
  }

  const int rbase = R0 + wr * 64 + lgrp * 4;
  const int cbase = C0 + wc * 64 + lrow;
  if (OUT_BF16) {
    bf16* C = (bf16*)Cv;
#pragma unroll
    for (int i = 0; i < 4; i++)
#pragma unroll
      for (int j = 0; j < 4; j++)
#pragma unroll
        for (int r = 0; r < 4; r++)
          C[(size_t)(rbase + i * 16 + r) * N + cbase + j * 16] = (bf16)acc[i][j][r];
  } else {
    float* C = (float*)Cv;
#pragma unroll
    for (int i = 0; i < 4; i++)
#pragma unroll
      for (int j = 0; j < 4; j++)
#pragma unroll
        for (int r = 0; r < 4; r++)
          C[(size_t)(rbase + i * 16 + r) * N + cbase + j * 16] = acc[i][j][r];
  }
}

// ---------- V transpose with sigma permutation baked in ----------
// Vt[(b*16+h)*64 + d][s'] = V[b][s][h][d],  s' = (s&~31) | ((s&15)<<1) | ((s>>4)&1)
__global__ __launch_bounds__(256) void transpose_v(const bf16* __restrict__ qkv,
                                                   bf16* __restrict__ Vt) {
  __shared__ bf16 sT[64 * 72];  // [d][s_local], stride 72 kills write conflicts
  const int tid = threadIdx.x;
  const int b = blockIdx.z, h = blockIdx.y, s0 = blockIdx.x * 64;
  const bf16* vsrc = qkv + (size_t)(b * S_TOK + s0) * E3 + h * 192 + 128;
#pragma unroll
  for (int j = 0; j < 8; j++) {
    int idx = tid + 256 * j;
    int sl = idx & 63, dp = idx >> 6;  // dp wave-uniform -> conflict-free writes
    unsigned u = *(const unsigned*)(vsrc + (size_t)sl * E3 + 2 * dp);
    sT[(2 * dp) * 72 + sl] = __builtin_bit_cast(bf16, (unsigned short)(u & 0xffffu));
    sT[(2 * dp + 1) * 72 + sl] = __builtin_bit_cast(bf16, (unsigned short)(u >> 16));
  }
  __syncthreads();
  bf16* vdst = Vt + ((size_t)(b * 16 + h) * 64) * S_TOK + s0;
#pragma unroll
  for (int j = 0; j < 2; j++) {
    int idx = tid + 256 * j;
    int d = idx >> 3, sc8 = (idx & 7) * 8;
    bf16x8 o;
#pragma unroll
    for (int m2 = 0; m2 < 8; m2++) {
      int sp = sc8 + m2;  // permuted position; invert sigma to find source s
      int ss = (sp & ~31) | ((sp >> 1) & 15) | ((sp & 1) << 4);
      o[m2] = sT[d * 72 + ss];
    }
    *(bf16x8*)(vdst + (size_t)d * S_TOK + sc8) = o;
  }
}

// ---------- fused attention v2: intra-block key-split for occupancy ----------
// block = 256 thr (4 waves); block owns ONE 64-row q-tile; wave w handles keys
// [w*512, (w+1)*512). Unnormalized partials combine linearly (no row-max needed):
// O = sum_w O_w, l = sum_w l_w  -> cross-wave LDS reduction in epilogue.
// 1024 blocks * 4 waves = 4096 waves = 4/SIMD (vs 1/SIMD in v1).
__global__ __launch_bounds__(256, 4) void attn(const bf16* __restrict__ qkv,
                                               const bf16* __restrict__ Vt,
                                               bf16* __restrict__ vals) {
  __shared__ bf16 sP[4][4][16 * 40];   // [wave][rowtile][16 rows x stride 40] 20 KB
  __shared__ float redO[4][16 * 72];   // per-wave partial O, one rowtile at a time, 18.4 KB
  __shared__ float redl[4][4][16];     // [wave][rowtile][row] partial row-sums, 1 KB

  const int tid = threadIdx.x;
  const int wv = tid >> 6, lane = tid & 63;
  const int lrow = lane & 15, lgrp = lane >> 4;
  const int b = blockIdx.z, h = blockIdx.y;
  const int qbase = blockIdx.x * 64;

  const bf16* qp = qkv + (size_t)(b * S_TOK + qbase) * E3 + h * 192;
  const bf16* kp = qkv + (size_t)(b * S_TOK) * E3 + h * 192 + 64;
  const bf16* vp = Vt + (size_t)((b * 16 + h) * 64) * S_TOK;

  // Q A-fragments hoisted to registers: A[m=lane&15][k=lgrp*8+j]
  bf16x8 qa[4][2];
#pragma unroll
  for (int rt = 0; rt < 4; rt++)
#pragma unroll
    for (int dh = 0; dh < 2; dh++)
      qa[rt][dh] = *(const bf16x8*)(qp + (size_t)(rt * 16 + lrow) * E3 + dh * 32 + lgrp * 8);

  floatx4 O[4][4] = {};
  floatx4 lacc[4] = {};
  bf16x8 ones;
  const bf16 one1 = (bf16)1.0f;
#pragma unroll
  for (int j = 0; j < 8; j++) ones[j] = one1;

  const float C8 = 0.18033688011f;  // 0.125 * log2(e)

  const int kt0 = wv * (S_TOK / 32 / 4);
  for (int kt = kt0; kt < kt0 + S_TOK / 32 / 4; kt++) {
    bf16x8 kf[2][2], vf[4];
#pragma unroll
    for (int t = 0; t < 2; t++)
#pragma unroll
      for (int dh = 0; dh < 2; dh++)
        kf[t][dh] = *(const bf16x8*)(kp + (size_t)(kt * 32 + t * 16 + lrow) * E3 + dh * 32 + lgrp * 8);
#pragma unroll
    for (int dt = 0; dt < 4; dt++)
      vf[dt] = *(const bf16x8*)(vp + (size_t)(dt * 16 + lrow) * S_TOK + kt * 32 + lgrp * 8);

    // QK^T, exp, pack P into LDS in A-layout-friendly order (sigma: cols 2c,2c+1)
#pragma unroll
    for (int rt = 0; rt < 4; rt++) {
      floatx4 sc0 = {0.f, 0.f, 0.f, 0.f}, sc1 = {0.f, 0.f, 0.f, 0.f};
      sc0 = MFMA16(qa[rt][0], kf[0][0], sc0);
      sc0 = MFMA16(qa[rt][1], kf[0][1], sc0);
      sc1 = MFMA16(qa[rt][0], kf[1][0], sc1);
      sc1 = MFMA16(qa[rt][1], kf[1][1], sc1);
#pragma unroll
      for (int r = 0; r < 4; r++) {
        float p0 = exp2f(sc0[r] * C8);
        float p1 = exp2f(sc1[r] * C8);
        unsigned u = (unsigned)__builtin_bit_cast(unsigned short, (bf16)p0) |
                     ((unsigned)__builtin_bit_cast(unsigned short, (bf16)p1) << 16);
        *(unsigned*)&sP[wv][rt][(lgrp * 4 + r) * 40 + lrow * 2] = u;
      }
    }
    // P back as A-frags; PV + row-sum via ones-column MFMA
#pragma unroll
    for (int rt = 0; rt < 4; rt++) {
      bf16x8 pf = *(const bf16x8*)&sP[wv][rt][lrow * 40 + lgrp * 8];
#pragma unroll
      for (int dt = 0; dt < 4; dt++) O[rt][dt] = MFMA16(pf, vf[dt], O[rt][dt]);
      lacc[rt] = MFMA16(pf, ones, lacc[rt]);
    }
  }

  // ---- cross-wave reduction: O = sum_w O_w, l = sum_w l_w, then normalize ----
  if (lrow == 0) {  // lanes 0,16,32,48 cover rows lgrp*4+r
#pragma unroll
    for (int rt = 0; rt < 4; rt++)
#pragma unroll
      for (int r = 0; r < 4; r++)
        redl[wv][rt][lgrp * 4 + r] = lacc[rt][r];
  }
  bf16* vout = vals + (size_t)(b * S_TOK + qbase) * DMODEL + h * 64;
#pragma unroll 1
  for (int rt = 0; rt < 4; rt++) {
    __syncthreads();  // prior rt's reads done (and redl visible for rt==0)
#pragma unroll
    for (int dt = 0; dt < 4; dt++)
#pragma unroll
      for (int r = 0; r < 4; r++)
        redO[wv][(lgrp * 4 + r) * 72 + dt * 16 + lrow] = O[rt][dt][r];
    __syncthreads();
    const int e = tid * 4;  // 256 threads x 4 elems = 16x64 tile
    const int row = e >> 6, col = e & 63;
    float ls = redl[0][rt][row] + redl[1][rt][row] + redl[2][rt][row] + redl[3][rt][row];
    float rinv = __builtin_amdgcn_rcpf(ls);
    float sx = 0.f, sy = 0.f, sz = 0.f, sw = 0.f;
#pragma unroll
    for (int w = 0; w < 4; w++) {
      const float4 t4 = *(const float4*)&redO[w][row * 72 + col];
      sx += t4.x; sy += t4.y; sz += t4.z; sw += t4.w;
    }
    bf16x4 o;
    o[0] = (bf16)(sx * rinv); o[1] = (bf16)(sy * rinv);
    o[2] = (bf16)(sz * rinv); o[3] = (bf16)(sw * rinv);
    *(bf16x4*)(vout + (size_t)(rt * 16 + row) * DMODEL + col) = o;
  }
}

// ---------- host ----------
extern "C" void kernel_launch(void* const* d_in, const int* in_sizes, int n_in,
                              void* d_out, int out_size, void* d_ws, size_t ws_size,
                              hipStream_t stream) {
  const float* X = (const float*)d_in[0];     // (2,2048,1024)
  const float* Wqkv = (const float*)d_in[1];  // (3072,1024)
  const float* Wout = (const float*)d_in[2];  // (1024,1024)
  float* out = (float*)d_out;                 // (2,2048,1024)

  char* ws = (char*)d_ws;
  bf16* Xb = (bf16*)(ws);                          //  8 MB
  bf16* Wqb = (bf16*)(ws + ((size_t)8 << 20));     //  6 MB
  bf16* Wob = (bf16*)(ws + ((size_t)14 << 20));    //  2 MB
  bf16* qkvb = (bf16*)(ws + ((size_t)16 << 20));   // 24 MB (4096 x 3072)
  bf16* Vt = (bf16*)(ws + ((size_t)40 << 20));     //  8 MB (2*16*64 x 2048)
  bf16* vals = (bf16*)(ws + ((size_t)48 << 20));   //  8 MB (4096 x 1024)

  cvt_f32_bf16<<<4194304 / 2048, 256, 0, stream>>>(X, Xb, 4194304);
  cvt_f32_bf16<<<3145728 / 2048, 256, 0, stream>>>(Wqkv, Wqb, 3145728);
  cvt_f32_bf16<<<1048576 / 2048, 256, 0, stream>>>(Wout, Wob, 1048576);

  // qkv = X @ Wqkv^T : (4096,1024)x(3072,1024)^T -> (4096,3072) bf16
  gemm_bt<true><<<dim3(24, 32), 256, 0, stream>>>(Xb, Wqb, qkvb, 4096, 3072, 1024);

  transpose_v<<<dim3(32, 16, 2), 256, 0, stream>>>(qkvb, Vt);

  attn<<<dim3(32, 16, 2), 256, 0, stream>>>(qkvb, Vt, vals);

  // out = vals @ Wout^T : (4096,1024)x(1024,1024)^T -> (4096,1024) fp32
  gemm_bt<false><<<dim3(8, 32), 256, 0, stream>>>(vals, Wob, out, 4096, 1024, 1024);
}

// Round 3
// 280.955 us; speedup vs baseline: 1.6277x; 1.6277x over previous
//
#include <hip/hip_runtime.h>
#include <cstdint>
#include <cstddef>

// ---------- types ----------
typedef __bf16 bf16;
typedef __bf16 bf16x8 __attribute__((ext_vector_type(8)));
typedef __bf16 bf16x4 __attribute__((ext_vector_type(4)));
typedef float  floatx4 __attribute__((ext_vector_type(4)));

typedef __attribute__((address_space(1))) void gvoid_t;
typedef __attribute__((address_space(3))) void lvoid_t;

#define MFMA16(a, b, c) __builtin_amdgcn_mfma_f32_16x16x32_bf16((a), (b), (c), 0, 0, 0)

// B=2, S=2048, D=1024, H=16, DH=64; tokens NT=4096; E3=3072
#define S_TOK 2048
#define E3 3072
#define DMODEL 1024

// ---------- fp32 -> bf16 convert ----------
__global__ __launch_bounds__(256) void cvt_f32_bf16(const float* __restrict__ s,
                                                    bf16* __restrict__ d, int n) {
  int i = (blockIdx.x * 256 + threadIdx.x) * 8;
  if (i >= n) return;
  const float4* p = (const float4*)(s + i);
  float4 a = p[0], b = p[1];
  bf16x8 o;
  o[0] = (bf16)a.x; o[1] = (bf16)a.y; o[2] = (bf16)a.z; o[3] = (bf16)a.w;
  o[4] = (bf16)b.x; o[5] = (bf16)b.y; o[6] = (bf16)b.z; o[7] = (bf16)b.w;
  *(bf16x8*)(d + i) = o;
}

// ---------- async global->LDS, 16B per lane ----------
__device__ __forceinline__ void gl_lds16(const bf16* g, bf16* l) {
  __builtin_amdgcn_global_load_lds((gvoid_t*)g, (lvoid_t*)l, 16, 0, 0);
}

// ---------- GEMM: C[m][n] = sum_k A[m][k] * Bt[n][k]  (m97 structure) ----------
// 128x128 tile, BK=32, 256 threads / 4 waves in 2x2, each wave 64x64 (4x4 MFMA tiles)
template <bool OUT_BF16>
__global__ __launch_bounds__(256) void gemm_bt(const bf16* __restrict__ A,
                                               const bf16* __restrict__ Bt,
                                               void* __restrict__ Cv,
                                               int M, int N, int K) {
  __shared__ bf16 sA[128 * 32];
  __shared__ bf16 sB[128 * 32];
  const int tid = threadIdx.x;
  const int wv = tid >> 6, lane = tid & 63;
  const int wr = wv >> 1, wc = wv & 1;
  const int lrow = lane & 15, lgrp = lane >> 4;
  const int R0 = blockIdx.y * 128, C0 = blockIdx.x * 128;

  floatx4 acc[4][4] = {};

  const bf16* gA = A + (size_t)(R0 + wv * 32 + (lane >> 2)) * K + (lane & 3) * 8;
  const bf16* gB = Bt + (size_t)(C0 + wv * 32 + (lane >> 2)) * K + (lane & 3) * 8;
  bf16* lA = sA + wv * 1024;  // wave-uniform LDS base; HW scatters lane i at +16B*i
  bf16* lB = sB + wv * 1024;
  const size_t rowstep = (size_t)16 * K;

  for (int k0 = 0; k0 < K; k0 += 32) {
    gl_lds16(gA + k0, lA);
    gl_lds16(gA + k0 + rowstep, lA + 512);
    gl_lds16(gB + k0, lB);
    gl_lds16(gB + k0 + rowstep, lB + 512);
    __syncthreads();  // drains vmcnt -> staged data visible
    bf16x8 af[4], bfr[4];
#pragma unroll
    for (int i = 0; i < 4; i++)
      af[i] = *(const bf16x8*)&sA[(wr * 64 + i * 16 + lrow) * 32 + lgrp * 8];
#pragma unroll
    for (int j = 0; j < 4; j++)
      bfr[j] = *(const bf16x8*)&sB[(wc * 64 + j * 16 + lrow) * 32 + lgrp * 8];
#pragma unroll
    for (int i = 0; i < 4; i++)
#pragma unroll
      for (int j = 0; j < 4; j++)
        acc[i][j] = MFMA16(af[i], bfr[j], acc[i][j]);
    __syncthreads();  // all waves done reading before restage
  }

  const int rbase = R0 + wr * 64 + lgrp * 4;
  const int cbase = C0 + wc * 64 + lrow;
  if (OUT_BF16) {
    bf16* C = (bf16*)Cv;
#pragma unroll
    for (int i = 0; i < 4; i++)
#pragma unroll
      for (int j = 0; j < 4; j++)
#pragma unroll
        for (int r = 0; r < 4; r++)
          C[(size_t)(rbase + i * 16 + r) * N + cbase + j * 16] = (bf16)acc[i][j][r];
  } else {
    float* C = (float*)Cv;
#pragma unroll
    for (int i = 0; i < 4; i++)
#pragma unroll
      for (int j = 0; j < 4; j++)
#pragma unroll
        for (int r = 0; r < 4; r++)
          C[(size_t)(rbase + i * 16 + r) * N + cbase + j * 16] = acc[i][j][r];
  }
}

// ---------- V transpose with sigma permutation baked in ----------
// Vt[(b*16+h)*64 + d][s'] = V[b][s][h][d],  s' = (s&~31) | ((s&15)<<1) | ((s>>4)&1)
__global__ __launch_bounds__(256) void transpose_v(const bf16* __restrict__ qkv,
                                                   bf16* __restrict__ Vt) {
  __shared__ bf16 sT[64 * 72];  // [d][s_local], stride 72 kills write conflicts
  const int tid = threadIdx.x;
  const int b = blockIdx.z, h = blockIdx.y, s0 = blockIdx.x * 64;
  const bf16* vsrc = qkv + (size_t)(b * S_TOK + s0) * E3 + h * 192 + 128;
#pragma unroll
  for (int j = 0; j < 8; j++) {
    int idx = tid + 256 * j;
    int sl = idx & 63, dp = idx >> 6;  // dp wave-uniform -> conflict-free writes
    unsigned u = *(const unsigned*)(vsrc + (size_t)sl * E3 + 2 * dp);
    sT[(2 * dp) * 72 + sl] = __builtin_bit_cast(bf16, (unsigned short)(u & 0xffffu));
    sT[(2 * dp + 1) * 72 + sl] = __builtin_bit_cast(bf16, (unsigned short)(u >> 16));
  }
  __syncthreads();
  bf16* vdst = Vt + ((size_t)(b * 16 + h) * 64) * S_TOK + s0;
#pragma unroll
  for (int j = 0; j < 2; j++) {
    int idx = tid + 256 * j;
    int d = idx >> 3, sc8 = (idx & 7) * 8;
    bf16x8 o;
#pragma unroll
    for (int m2 = 0; m2 < 8; m2++) {
      int sp = sc8 + m2;  // permuted position; invert sigma to find source s
      int ss = (sp & ~31) | ((sp >> 1) & 15) | ((sp & 1) << 4);
      o[m2] = sT[d * 72 + ss];
    }
    *(bf16x8*)(vdst + (size_t)d * S_TOK + sc8) = o;
  }
}

// ---------- fused attention v3: 2x2 (row-half x key-half) wave split ----------
// block = 256 thr (4 waves) owns a 64-row q-tile. Wave w: rows 32*(w>>1)..+32,
// keys 1024*(w&1)..+1024. Live set per wave ~110 VGPRs incl. accumulators ->
// fits the 128-reg budget of 4 waves/SIMD with NO scratch spill (R2's failure
// mode: O[4][4] forced 654 MB of spill traffic).
// Partials combine linearly (scores bounded, no row-max): O=O_w0+O_w1, l likewise.
__global__ __launch_bounds__(256, 4) void attn(const bf16* __restrict__ qkv,
                                               const bf16* __restrict__ Vt,
                                               bf16* __restrict__ vals) {
  __shared__ bf16 sP[4][2][16 * 40];   // [wave][rowtile][16 x stride40]  10.2 KB
  __shared__ float redO[4][16 * 72];   // per-wave partial O, rowtile-at-a-time, 18.4 KB
  __shared__ float redl[4][2][16];     // [wave][rowtile][row] partial row-sums, 0.5 KB

  const int tid = threadIdx.x;
  const int wv = tid >> 6, lane = tid & 63;
  const int wrow = wv >> 1, wkey = wv & 1;
  const int lrow = lane & 15, lgrp = lane >> 4;
  const int b = blockIdx.z, h = blockIdx.y;
  const int qbase = blockIdx.x * 64;

  const bf16* qp = qkv + (size_t)(b * S_TOK + qbase + wrow * 32) * E3 + h * 192;
  const bf16* kp = qkv + (size_t)(b * S_TOK) * E3 + h * 192 + 64;
  const bf16* vp = Vt + (size_t)((b * 16 + h) * 64) * S_TOK;

  // Q A-fragments hoisted to registers: A[m=lane&15][k=lgrp*8+j]
  bf16x8 qa[2][2];
#pragma unroll
  for (int rt = 0; rt < 2; rt++)
#pragma unroll
    for (int dh = 0; dh < 2; dh++)
      qa[rt][dh] = *(const bf16x8*)(qp + (size_t)(rt * 16 + lrow) * E3 + dh * 32 + lgrp * 8);

  floatx4 O[2][4] = {};
  floatx4 lacc[2] = {};
  bf16x8 ones;
  const bf16 one1 = (bf16)1.0f;
#pragma unroll
  for (int j = 0; j < 8; j++) ones[j] = one1;

  const float C8 = 0.18033688011f;  // 0.125 * log2(e)

  const int kt0 = wkey * (S_TOK / 32 / 2);
  for (int kt = kt0; kt < kt0 + S_TOK / 32 / 2; kt++) {
    bf16x8 kf[2][2], vf[4];
#pragma unroll
    for (int t = 0; t < 2; t++)
#pragma unroll
      for (int dh = 0; dh < 2; dh++)
        kf[t][dh] = *(const bf16x8*)(kp + (size_t)(kt * 32 + t * 16 + lrow) * E3 + dh * 32 + lgrp * 8);
#pragma unroll
    for (int dt = 0; dt < 4; dt++)
      vf[dt] = *(const bf16x8*)(vp + (size_t)(dt * 16 + lrow) * S_TOK + kt * 32 + lgrp * 8);

    // QK^T, exp, pack P into LDS in A-layout-friendly order (sigma: cols 2c,2c+1)
#pragma unroll
    for (int rt = 0; rt < 2; rt++) {
      floatx4 sc0 = {0.f, 0.f, 0.f, 0.f}, sc1 = {0.f, 0.f, 0.f, 0.f};
      sc0 = MFMA16(qa[rt][0], kf[0][0], sc0);
      sc0 = MFMA16(qa[rt][1], kf[0][1], sc0);
      sc1 = MFMA16(qa[rt][0], kf[1][0], sc1);
      sc1 = MFMA16(qa[rt][1], kf[1][1], sc1);
#pragma unroll
      for (int r = 0; r < 4; r++) {
        float p0 = exp2f(sc0[r] * C8);
        float p1 = exp2f(sc1[r] * C8);
        unsigned u = (unsigned)__builtin_bit_cast(unsigned short, (bf16)p0) |
                     ((unsigned)__builtin_bit_cast(unsigned short, (bf16)p1) << 16);
        *(unsigned*)&sP[wv][rt][(lgrp * 4 + r) * 40 + lrow * 2] = u;
      }
    }
    // P back as A-frags; PV + row-sum via ones-column MFMA
#pragma unroll
    for (int rt = 0; rt < 2; rt++) {
      bf16x8 pf = *(const bf16x8*)&sP[wv][rt][lrow * 40 + lgrp * 8];
#pragma unroll
      for (int dt = 0; dt < 4; dt++) O[rt][dt] = MFMA16(pf, vf[dt], O[rt][dt]);
      lacc[rt] = MFMA16(pf, ones, lacc[rt]);
    }
  }

  // ---- pairwise cross-wave reduction (waves 2p, 2p+1 share rows), normalize ----
  if (lrow == 0) {  // lanes 0,16,32,48 cover rows lgrp*4+r
#pragma unroll
    for (int rt = 0; rt < 2; rt++)
#pragma unroll
      for (int r = 0; r < 4; r++)
        redl[wv][rt][lgrp * 4 + r] = lacc[rt][r];
  }
  bf16* vout = vals + (size_t)(b * S_TOK + qbase) * DMODEL + h * 64;
#pragma unroll 1
  for (int rt = 0; rt < 2; rt++) {
    __syncthreads();  // prior rt's reads done (and redl visible for rt==0)
#pragma unroll
    for (int dt = 0; dt < 4; dt++)
#pragma unroll
      for (int r = 0; r < 4; r++)
        redO[wv][(lgrp * 4 + r) * 72 + dt * 16 + lrow] = O[rt][dt][r];
    __syncthreads();
    // 256 threads reduce both pairs: pair p covers q-rows p*32 + rt*16 + [0,16)
    const int p = tid >> 7, t2 = tid & 127;
    const int row = t2 >> 3, col = (t2 & 7) * 8;
    float ls = redl[2 * p][rt][row] + redl[2 * p + 1][rt][row];
    float rinv = __builtin_amdgcn_rcpf(ls);
    const float4 a0 = *(const float4*)&redO[2 * p][row * 72 + col];
    const float4 a1 = *(const float4*)&redO[2 * p][row * 72 + col + 4];
    const float4 b0 = *(const float4*)&redO[2 * p + 1][row * 72 + col];
    const float4 b1 = *(const float4*)&redO[2 * p + 1][row * 72 + col + 4];
    bf16x8 o;
    o[0] = (bf16)((a0.x + b0.x) * rinv); o[1] = (bf16)((a0.y + b0.y) * rinv);
    o[2] = (bf16)((a0.z + b0.z) * rinv); o[3] = (bf16)((a0.w + b0.w) * rinv);
    o[4] = (bf16)((a1.x + b1.x) * rinv); o[5] = (bf16)((a1.y + b1.y) * rinv);
    o[6] = (bf16)((a1.z + b1.z) * rinv); o[7] = (bf16)((a1.w + b1.w) * rinv);
    *(bf16x8*)(vout + (size_t)(p * 32 + rt * 16 + row) * DMODEL + col) = o;
  }
}

// ---------- host ----------
extern "C" void kernel_launch(void* const* d_in, const int* in_sizes, int n_in,
                              void* d_out, int out_size, void* d_ws, size_t ws_size,
                              hipStream_t stream) {
  const float* X = (const float*)d_in[0];     // (2,2048,1024)
  const float* Wqkv = (const float*)d_in[1];  // (3072,1024)
  const float* Wout = (const float*)d_in[2];  // (1024,1024)
  float* out = (float*)d_out;                 // (2,2048,1024)

  char* ws = (char*)d_ws;
  bf16* Xb = (bf16*)(ws);                          //  8 MB
  bf16* Wqb = (bf16*)(ws + ((size_t)8 << 20));     //  6 MB
  bf16* Wob = (bf16*)(ws + ((size_t)14 << 20));    //  2 MB
  bf16* qkvb = (bf16*)(ws + ((size_t)16 << 20));   // 24 MB (4096 x 3072)
  bf16* Vt = (bf16*)(ws + ((size_t)40 << 20));     //  8 MB (2*16*64 x 2048)
  bf16* vals = (bf16*)(ws + ((size_t)48 << 20));   //  8 MB (4096 x 1024)

  cvt_f32_bf16<<<4194304 / 2048, 256, 0, stream>>>(X, Xb, 4194304);
  cvt_f32_bf16<<<3145728 / 2048, 256, 0, stream>>>(Wqkv, Wqb, 3145728);
  cvt_f32_bf16<<<1048576 / 2048, 256, 0, stream>>>(Wout, Wob, 1048576);

  // qkv = X @ Wqkv^T : (4096,1024)x(3072,1024)^T -> (4096,3072) bf16
  gemm_bt<true><<<dim3(24, 32), 256, 0, stream>>>(Xb, Wqb, qkvb, 4096, 3072, 1024);

  transpose_v<<<dim3(32, 16, 2), 256, 0, stream>>>(qkvb, Vt);

  attn<<<dim3(32, 16, 2), 256, 0, stream>>>(qkvb, Vt, vals);

  // out = vals @ Wout^T : (4096,1024)x(1024,1024)^T -> (4096,1024) fp32
  gemm_bt<false><<<dim3(8, 32), 256, 0, stream>>>(vals, Wob, out, 4096, 1024, 1024);
}

// Round 5
// 280.399 us; speedup vs baseline: 1.6309x; 1.0020x over previous
//
#include <hip/hip_runtime.h>
#include <cstdint>
#include <cstddef>

// ---------- types ----------
typedef __bf16 bf16;
typedef __bf16 bf16x8 __attribute__((ext_vector_type(8)));
typedef __bf16 bf16x4 __attribute__((ext_vector_type(4)));
typedef __bf16 bf16x2 __attribute__((ext_vector_type(2)));
typedef float  floatx4 __attribute__((ext_vector_type(4)));

typedef __attribute__((address_space(1))) void gvoid_t;
typedef __attribute__((address_space(3))) void lvoid_t;

#define MFMA16(a, b, c) __builtin_amdgcn_mfma_f32_16x16x32_bf16((a), (b), (c), 0, 0, 0)

#if __has_builtin(__builtin_amdgcn_exp2f)
#define EXP2(x) __builtin_amdgcn_exp2f(x)
#else
#define EXP2(x) exp2f(x)
#endif

// B=2, S=2048, D=1024, H=16, DH=64; tokens NT=4096; E3=3072
#define S_TOK 2048
#define E3 3072
#define DMODEL 1024

// ---------- fp32 -> bf16 convert ----------
__global__ __launch_bounds__(256) void cvt_f32_bf16(const float* __restrict__ s,
                                                    bf16* __restrict__ d, int n) {
  int i = (blockIdx.x * 256 + threadIdx.x) * 8;
  if (i >= n) return;
  const float4* p = (const float4*)(s + i);
  float4 a = p[0], b = p[1];
  bf16x8 o;
  o[0] = (bf16)a.x; o[1] = (bf16)a.y; o[2] = (bf16)a.z; o[3] = (bf16)a.w;
  o[4] = (bf16)b.x; o[5] = (bf16)b.y; o[6] = (bf16)b.z; o[7] = (bf16)b.w;
  *(bf16x8*)(d + i) = o;
}

// ---------- W_qkv convert with softmax scale pre-folded into Q rows ----------
// Row e of W_qkv: e%192 in [0,64) produces Q -> scale by 0.125*log2(e) so the
// attn kernel can use exp2(score) directly (deletes 16 v_mul per wave-iter).
__global__ __launch_bounds__(256) void cvt_wqkv(const float* __restrict__ s,
                                                bf16* __restrict__ d, int n) {
  int i = (blockIdx.x * 256 + threadIdx.x) * 8;
  if (i >= n) return;
  int row = i >> 10;  // D=1024 per row
  float sc = ((row % 192) < 64) ? 0.18033688011f : 1.0f;
  const float4* p = (const float4*)(s + i);
  float4 a = p[0], b = p[1];
  bf16x8 o;
  o[0] = (bf16)(a.x * sc); o[1] = (bf16)(a.y * sc);
  o[2] = (bf16)(a.z * sc); o[3] = (bf16)(a.w * sc);
  o[4] = (bf16)(b.x * sc); o[5] = (bf16)(b.y * sc);
  o[6] = (bf16)(b.z * sc); o[7] = (bf16)(b.w * sc);
  *(bf16x8*)(d + i) = o;
}

// ---------- async global->LDS, 16B per lane ----------
__device__ __forceinline__ void gl_lds16(const bf16* g, bf16* l) {
  __builtin_amdgcn_global_load_lds((gvoid_t*)g, (lvoid_t*)l, 16, 0, 0);
}

// ---------- GEMM: C[m][n] = sum_k A[m][k] * Bt[n][k]  (m97 structure) ----------
// 128x128 tile, BK=32, 256 threads / 4 waves in 2x2, each wave 64x64 (4x4 MFMA tiles)
template <bool OUT_BF16>
__global__ __launch_bounds__(256) void gemm_bt(const bf16* __restrict__ A,
                                               const bf16* __restrict__ Bt,
                                               void* __restrict__ Cv,
                                               int M, int N, int K) {
  __shared__ bf16 sA[128 * 32];
  __shared__ bf16 sB[128 * 32];
  const int tid = threadIdx.x;
  const int wv = tid >> 6, lane = tid & 63;
  const int wr = wv >> 1, wc = wv & 1;
  const int lrow = lane & 15, lgrp = lane >> 4;
  const int R0 = blockIdx.y * 128, C0 = blockIdx.x * 128;

  floatx4 acc[4][4] = {};

  const bf16* gA = A + (size_t)(R0 + wv * 32 + (lane >> 2)) * K + (lane & 3) * 8;
  const bf16* gB = Bt + (size_t)(C0 + wv * 32 + (lane >> 2)) * K + (lane & 3) * 8;
  bf16* lA = sA + wv * 1024;  // wave-uniform LDS base; HW scatters lane i at +16B*i
  bf16* lB = sB + wv * 1024;
  const size_t rowstep = (size_t)16 * K;

  for (int k0 = 0; k0 < K; k0 += 32) {
    gl_lds16(gA + k0, lA);
    gl_lds16(gA + k0 + rowstep, lA + 512);
    gl_lds16(gB + k0, lB);
    gl_lds16(gB + k0 + rowstep, lB + 512);
    __syncthreads();  // drains vmcnt -> staged data visible
    bf16x8 af[4], bfr[4];
#pragma unroll
    for (int i = 0; i < 4; i++)
      af[i] = *(const bf16x8*)&sA[(wr * 64 + i * 16 + lrow) * 32 + lgrp * 8];
#pragma unroll
    for (int j = 0; j < 4; j++)
      bfr[j] = *(const bf16x8*)&sB[(wc * 64 + j * 16 + lrow) * 32 + lgrp * 8];
#pragma unroll
    for (int i = 0; i < 4; i++)
#pragma unroll
      for (int j = 0; j < 4; j++)
        acc[i][j] = MFMA16(af[i], bfr[j], acc[i][j]);
    __syncthreads();  // all waves done reading before restage
  }

  const int rbase = R0 + wr * 64 + lgrp * 4;
  const int cbase = C0 + wc * 64 + lrow;
  if (OUT_BF16) {
    bf16* C = (bf16*)Cv;
#pragma unroll
    for (int i = 0; i < 4; i++)
#pragma unroll
      for (int j = 0; j < 4; j++)
#pragma unroll
        for (int r = 0; r < 4; r++)
          C[(size_t)(rbase + i * 16 + r) * N + cbase + j * 16] = (bf16)acc[i][j][r];
  } else {
    float* C = (float*)Cv;
#pragma unroll
    for (int i = 0; i < 4; i++)
#pragma unroll
      for (int j = 0; j < 4; j++)
#pragma unroll
        for (int r = 0; r < 4; r++)
          C[(size_t)(rbase + i * 16 + r) * N + cbase + j * 16] = acc[i][j][r];
  }
}

// ---------- V transpose with sigma permutation baked in ----------
// Vt[(b*16+h)*64 + d][s'] = V[b][s][h][d],  s' = (s&~31) | ((s&15)<<1) | ((s>>4)&1)
__global__ __launch_bounds__(256) void transpose_v(const bf16* __restrict__ qkv,
                                                   bf16* __restrict__ Vt) {
  __shared__ bf16 sT[64 * 72];  // [d][s_local], stride 72 kills write conflicts
  const int tid = threadIdx.x;
  const int b = blockIdx.z, h = blockIdx.y, s0 = blockIdx.x * 64;
  const bf16* vsrc = qkv + (size_t)(b * S_TOK + s0) * E3 + h * 192 + 128;
#pragma unroll
  for (int j = 0; j < 8; j++) {
    int idx = tid + 256 * j;
    int sl = idx & 63, dp = idx >> 6;  // dp wave-uniform -> conflict-free writes
    unsigned u = *(const unsigned*)(vsrc + (size_t)sl * E3 + 2 * dp);
    sT[(2 * dp) * 72 + sl] = __builtin_bit_cast(bf16, (unsigned short)(u & 0xffffu));
    sT[(2 * dp + 1) * 72 + sl] = __builtin_bit_cast(bf16, (unsigned short)(u >> 16));
  }
  __syncthreads();
  bf16* vdst = Vt + ((size_t)(b * 16 + h) * 64) * S_TOK + s0;
#pragma unroll
  for (int j = 0; j < 2; j++) {
    int idx = tid + 256 * j;
    int d = idx >> 3, sc8 = (idx & 7) * 8;
    bf16x8 o;
#pragma unroll
    for (int m2 = 0; m2 < 8; m2++) {
      int sp = sc8 + m2;  // permuted position; invert sigma to find source s
      int ss = (sp & ~31) | ((sp >> 1) & 15) | ((sp & 1) << 4);
      o[m2] = sT[d * 72 + ss];
    }
    *(bf16x8*)(vdst + (size_t)d * S_TOK + sc8) = o;
  }
}

// ---------- fused attention v4: v3 structure, spill-free at (256,3) ----------
// block = 256 thr (4 waves) owns a 64-row q-tile. Wave w: rows 32*(w>>1)..+32,
// keys 1024*(w&1)..+1024. 168-reg budget (3 waves/SIMD) fits the ~150-reg live
// set with NO scratch (R3 at (256,4): 64+64 split -> 64 MB spill traffic).
// Q pre-scaled by 0.125*log2e in cvt_wqkv -> exp2 directly on scores.
__global__ __launch_bounds__(256, 3) void attn(const bf16* __restrict__ qkv,
                                               const bf16* __restrict__ Vt,
                                               bf16* __restrict__ vals) {
  __shared__ bf16 sP[4][2][16 * 40];   // [wave][rowtile][16 x stride40]  10.2 KB
  __shared__ float redO[4][16 * 72];   // per-wave partial O, rowtile-at-a-time, 18.4 KB
  __shared__ float redl[4][2][16];     // [wave][rowtile][row] partial row-sums, 0.5 KB

  const int tid = threadIdx.x;
  const int wv = tid >> 6, lane = tid & 63;
  const int wrow = wv >> 1, wkey = wv & 1;
  const int lrow = lane & 15, lgrp = lane >> 4;
  const int b = blockIdx.z, h = blockIdx.y;
  const int qbase = blockIdx.x * 64;

  const bf16* qp = qkv + (size_t)(b * S_TOK + qbase + wrow * 32) * E3 + h * 192;
  const bf16* kp = qkv + (size_t)(b * S_TOK) * E3 + h * 192 + 64;
  const bf16* vp = Vt + (size_t)((b * 16 + h) * 64) * S_TOK;

  // Q A-fragments hoisted to registers: A[m=lane&15][k=lgrp*8+j]
  bf16x8 qa[2][2];
#pragma unroll
  for (int rt = 0; rt < 2; rt++)
#pragma unroll
    for (int dh = 0; dh < 2; dh++)
      qa[rt][dh] = *(const bf16x8*)(qp + (size_t)(rt * 16 + lrow) * E3 + dh * 32 + lgrp * 8);

  floatx4 O[2][4] = {};
  floatx4 lacc[2] = {};
  bf16x8 ones;
  const bf16 one1 = (bf16)1.0f;
#pragma unroll
  for (int j = 0; j < 8; j++) ones[j] = one1;

  const int kt0 = wkey * (S_TOK / 32 / 2);
  for (int kt = kt0; kt < kt0 + S_TOK / 32 / 2; kt++) {
    bf16x8 kf[2][2], vf[4];
#pragma unroll
    for (int t = 0; t < 2; t++)
#pragma unroll
      for (int dh = 0; dh < 2; dh++)
        kf[t][dh] = *(const bf16x8*)(kp + (size_t)(kt * 32 + t * 16 + lrow) * E3 + dh * 32 + lgrp * 8);
#pragma unroll
    for (int dt = 0; dt < 4; dt++)
      vf[dt] = *(const bf16x8*)(vp + (size_t)(dt * 16 + lrow) * S_TOK + kt * 32 + lgrp * 8);

    // QK^T (pre-scaled), exp2, pack P to LDS in A-layout order (sigma cols 2c,2c+1)
#pragma unroll
    for (int rt = 0; rt < 2; rt++) {
      floatx4 sc0 = {0.f, 0.f, 0.f, 0.f}, sc1 = {0.f, 0.f, 0.f, 0.f};
      sc0 = MFMA16(qa[rt][0], kf[0][0], sc0);
      sc0 = MFMA16(qa[rt][1], kf[0][1], sc0);
      sc1 = MFMA16(qa[rt][0], kf[1][0], sc1);
      sc1 = MFMA16(qa[rt][1], kf[1][1], sc1);
#pragma unroll
      for (int r = 0; r < 4; r++) {
        bf16x2 h2;
        h2[0] = (bf16)EXP2(sc0[r]);
        h2[1] = (bf16)EXP2(sc1[r]);
        *(unsigned*)&sP[wv][rt][(lgrp * 4 + r) * 40 + lrow * 2] =
            __builtin_bit_cast(unsigned, h2);
      }
    }
    // P back as A-frags; PV + row-sum via ones-column MFMA
#pragma unroll
    for (int rt = 0; rt < 2; rt++) {
      bf16x8 pf = *(const bf16x8*)&sP[wv][rt][lrow * 40 + lgrp * 8];
#pragma unroll
      for (int dt = 0; dt < 4; dt++) O[rt][dt] = MFMA16(pf, vf[dt], O[rt][dt]);
      lacc[rt] = MFMA16(pf, ones, lacc[rt]);
    }
  }

  // ---- pairwise cross-wave reduction (waves 2p, 2p+1 share rows), normalize ----
  if (lrow == 0) {  // lanes 0,16,32,48 cover rows lgrp*4+r
#pragma unroll
    for (int rt = 0; rt < 2; rt++)
#pragma unroll
      for (int r = 0; r < 4; r++)
        redl[wv][rt][lgrp * 4 + r] = lacc[rt][r];
  }
  bf16* vout = vals + (size_t)(b * S_TOK + qbase) * DMODEL + h * 64;
#pragma unroll 1
  for (int rt = 0; rt < 2; rt++) {
    __syncthreads();  // prior rt's reads done (and redl visible for rt==0)
#pragma unroll
    for (int dt = 0; dt < 4; dt++)
#pragma unroll
      for (int r = 0; r < 4; r++)
        redO[wv][(lgrp * 4 + r) * 72 + dt * 16 + lrow] = O[rt][dt][r];
    __syncthreads();
    // 256 threads reduce both pairs: pair p covers q-rows p*32 + rt*16 + [0,16)
    const int p = tid >> 7, t2 = tid & 127;
    const int row = t2 >> 3, col = (t2 & 7) * 8;
    float ls = redl[2 * p][rt][row] + redl[2 * p + 1][rt][row];
    float rinv = __builtin_amdgcn_rcpf(ls);
    const float4 a0 = *(const float4*)&redO[2 * p][row * 72 + col];
    const float4 a1 = *(const float4*)&redO[2 * p][row * 72 + col + 4];
    const float4 b0 = *(const float4*)&redO[2 * p + 1][row * 72 + col];
    const float4 b1 = *(const float4*)&redO[2 * p + 1][row * 72 + col + 4];
    bf16x8 o;
    o[0] = (bf16)((a0.x + b0.x) * rinv); o[1] = (bf16)((a0.y + b0.y) * rinv);
    o[2] = (bf16)((a0.z + b0.z) * rinv); o[3] = (bf16)((a0.w + b0.w) * rinv);
    o[4] = (bf16)((a1.x + b1.x) * rinv); o[5] = (bf16)((a1.y + b1.y) * rinv);
    o[6] = (bf16)((a1.z + b1.z) * rinv); o[7] = (bf16)((a1.w + b1.w) * rinv);
    *(bf16x8*)(vout + (size_t)(p * 32 + rt * 16 + row) * DMODEL + col) = o;
  }
}

// ---------- host ----------
extern "C" void kernel_launch(void* const* d_in, const int* in_sizes, int n_in,
                              void* d_out, int out_size, void* d_ws, size_t ws_size,
                              hipStream_t stream) {
  const float* X = (const float*)d_in[0];     // (2,2048,1024)
  const float* Wqkv = (const float*)d_in[1];  // (3072,1024)
  const float* Wout = (const float*)d_in[2];  // (1024,1024)
  float* out = (float*)d_out;                 // (2,2048,1024)

  char* ws = (char*)d_ws;
  bf16* Xb = (bf16*)(ws);                          //  8 MB
  bf16* Wqb = (bf16*)(ws + ((size_t)8 << 20));     //  6 MB
  bf16* Wob = (bf16*)(ws + ((size_t)14 << 20));    //  2 MB
  bf16* qkvb = (bf16*)(ws + ((size_t)16 << 20));   // 24 MB (4096 x 3072)
  bf16* Vt = (bf16*)(ws + ((size_t)40 << 20));     //  8 MB (2*16*64 x 2048)
  bf16* vals = (bf16*)(ws + ((size_t)48 << 20));   //  8 MB (4096 x 1024)

  cvt_f32_bf16<<<4194304 / 2048, 256, 0, stream>>>(X, Xb, 4194304);
  cvt_wqkv<<<3145728 / 2048, 256, 0, stream>>>(Wqkv, Wqb, 3145728);
  cvt_f32_bf16<<<1048576 / 2048, 256, 0, stream>>>(Wout, Wob, 1048576);

  // qkv = X @ Wqkv^T : (4096,1024)x(3072,1024)^T -> (4096,3072) bf16
  gemm_bt<true><<<dim3(24, 32), 256, 0, stream>>>(Xb, Wqb, qkvb, 4096, 3072, 1024);

  transpose_v<<<dim3(32, 16, 2), 256, 0, stream>>>(qkvb, Vt);

  attn<<<dim3(32, 16, 2), 256, 0, stream>>>(qkvb, Vt, vals);

  // out = vals @ Wout^T : (4096,1024)x(1024,1024)^T -> (4096,1024) fp32
  gemm_bt<false><<<dim3(8, 32), 256, 0, stream>>>(vals, Wob, out, 4096, 1024, 1024);
}

// Round 6
// 268.860 us; speedup vs baseline: 1.7009x; 1.0429x over previous
//
#include <hip/hip_runtime.h>
#include <cstdint>
#include <cstddef>

// ---------- types ----------
typedef __bf16 bf16;
typedef __bf16 bf16x8 __attribute__((ext_vector_type(8)));
typedef __bf16 bf16x4 __attribute__((ext_vector_type(4)));
typedef __bf16 bf16x2 __attribute__((ext_vector_type(2)));
typedef float  floatx4 __attribute__((ext_vector_type(4)));

typedef __attribute__((address_space(1))) void gvoid_t;
typedef __attribute__((address_space(3))) void lvoid_t;

#define MFMA16(a, b, c) __builtin_amdgcn_mfma_f32_16x16x32_bf16((a), (b), (c), 0, 0, 0)

#if __has_builtin(__builtin_amdgcn_exp2f)
#define EXP2(x) __builtin_amdgcn_exp2f(x)
#else
#define EXP2(x) exp2f(x)
#endif

// B=2, S=2048, D=1024, H=16, DH=64; tokens NT=4096; E3=3072
#define S_TOK 2048
#define E3 3072
#define DMODEL 1024

// ---------- fp32 -> bf16 convert ----------
__global__ __launch_bounds__(256) void cvt_f32_bf16(const float* __restrict__ s,
                                                    bf16* __restrict__ d, int n) {
  int i = (blockIdx.x * 256 + threadIdx.x) * 8;
  if (i >= n) return;
  const float4* p = (const float4*)(s + i);
  float4 a = p[0], b = p[1];
  bf16x8 o;
  o[0] = (bf16)a.x; o[1] = (bf16)a.y; o[2] = (bf16)a.z; o[3] = (bf16)a.w;
  o[4] = (bf16)b.x; o[5] = (bf16)b.y; o[6] = (bf16)b.z; o[7] = (bf16)b.w;
  *(bf16x8*)(d + i) = o;
}

// ---------- W_qkv convert with softmax scale pre-folded into Q rows ----------
// Row e of W_qkv: e%192 in [0,64) produces Q -> scale by 0.125*log2(e) so the
// attn kernel can use exp2(score) directly.
__global__ __launch_bounds__(256) void cvt_wqkv(const float* __restrict__ s,
                                                bf16* __restrict__ d, int n) {
  int i = (blockIdx.x * 256 + threadIdx.x) * 8;
  if (i >= n) return;
  int row = i >> 10;  // D=1024 per row
  float sc = ((row % 192) < 64) ? 0.18033688011f : 1.0f;
  const float4* p = (const float4*)(s + i);
  float4 a = p[0], b = p[1];
  bf16x8 o;
  o[0] = (bf16)(a.x * sc); o[1] = (bf16)(a.y * sc);
  o[2] = (bf16)(a.z * sc); o[3] = (bf16)(a.w * sc);
  o[4] = (bf16)(b.x * sc); o[5] = (bf16)(b.y * sc);
  o[6] = (bf16)(b.z * sc); o[7] = (bf16)(b.w * sc);
  *(bf16x8*)(d + i) = o;
}

// ---------- async global->LDS, 16B per lane ----------
__device__ __forceinline__ void gl_lds16(const bf16* g, bf16* l) {
  __builtin_amdgcn_global_load_lds((gvoid_t*)g, (lvoid_t*)l, 16, 0, 0);
}

// ---------- GEMM: C[m][n] = sum_k A[m][k] * Bt[n][k]  (m97 structure) ----------
// 128x128 tile, BK=32, 256 threads / 4 waves in 2x2, each wave 64x64 (4x4 MFMA tiles)
template <bool OUT_BF16>
__global__ __launch_bounds__(256) void gemm_bt(const bf16* __restrict__ A,
                                               const bf16* __restrict__ Bt,
                                               void* __restrict__ Cv,
                                               int M, int N, int K) {
  __shared__ bf16 sA[128 * 32];
  __shared__ bf16 sB[128 * 32];
  const int tid = threadIdx.x;
  const int wv = tid >> 6, lane = tid & 63;
  const int wr = wv >> 1, wc = wv & 1;
  const int lrow = lane & 15, lgrp = lane >> 4;
  const int R0 = blockIdx.y * 128, C0 = blockIdx.x * 128;

  floatx4 acc[4][4] = {};

  const bf16* gA = A + (size_t)(R0 + wv * 32 + (lane >> 2)) * K + (lane & 3) * 8;
  const bf16* gB = Bt + (size_t)(C0 + wv * 32 + (lane >> 2)) * K + (lane & 3) * 8;
  bf16* lA = sA + wv * 1024;  // wave-uniform LDS base; HW scatters lane i at +16B*i
  bf16* lB = sB + wv * 1024;
  const size_t rowstep = (size_t)16 * K;

  for (int k0 = 0; k0 < K; k0 += 32) {
    gl_lds16(gA + k0, lA);
    gl_lds16(gA + k0 + rowstep, lA + 512);
    gl_lds16(gB + k0, lB);
    gl_lds16(gB + k0 + rowstep, lB + 512);
    __syncthreads();  // drains vmcnt -> staged data visible
    bf16x8 af[4], bfr[4];
#pragma unroll
    for (int i = 0; i < 4; i++)
      af[i] = *(const bf16x8*)&sA[(wr * 64 + i * 16 + lrow) * 32 + lgrp * 8];
#pragma unroll
    for (int j = 0; j < 4; j++)
      bfr[j] = *(const bf16x8*)&sB[(wc * 64 + j * 16 + lrow) * 32 + lgrp * 8];
#pragma unroll
    for (int i = 0; i < 4; i++)
#pragma unroll
      for (int j = 0; j < 4; j++)
        acc[i][j] = MFMA16(af[i], bfr[j], acc[i][j]);
    __syncthreads();  // all waves done reading before restage
  }

  const int rbase = R0 + wr * 64 + lgrp * 4;
  const int cbase = C0 + wc * 64 + lrow;
  if (OUT_BF16) {
    bf16* C = (bf16*)Cv;
#pragma unroll
    for (int i = 0; i < 4; i++)
#pragma unroll
      for (int j = 0; j < 4; j++)
#pragma unroll
        for (int r = 0; r < 4; r++)
          C[(size_t)(rbase + i * 16 + r) * N + cbase + j * 16] = (bf16)acc[i][j][r];
  } else {
    float* C = (float*)Cv;
#pragma unroll
    for (int i = 0; i < 4; i++)
#pragma unroll
      for (int j = 0; j < 4; j++)
#pragma unroll
        for (int r = 0; r < 4; r++)
          C[(size_t)(rbase + i * 16 + r) * N + cbase + j * 16] = acc[i][j][r];
  }
}

// ---------- V transpose with sigma permutation baked in ----------
// Vt[(b*16+h)*64 + d][s'] = V[b][s][h][d],  s' = (s&~31) | ((s&15)<<1) | ((s>>4)&1)
__global__ __launch_bounds__(256) void transpose_v(const bf16* __restrict__ qkv,
                                                   bf16* __restrict__ Vt) {
  __shared__ bf16 sT[64 * 72];  // [d][s_local], stride 72 kills write conflicts
  const int tid = threadIdx.x;
  const int b = blockIdx.z, h = blockIdx.y, s0 = blockIdx.x * 64;
  const bf16* vsrc = qkv + (size_t)(b * S_TOK + s0) * E3 + h * 192 + 128;
#pragma unroll
  for (int j = 0; j < 8; j++) {
    int idx = tid + 256 * j;
    int sl = idx & 63, dp = idx >> 6;  // dp wave-uniform -> conflict-free writes
    unsigned u = *(const unsigned*)(vsrc + (size_t)sl * E3 + 2 * dp);
    sT[(2 * dp) * 72 + sl] = __builtin_bit_cast(bf16, (unsigned short)(u & 0xffffu));
    sT[(2 * dp + 1) * 72 + sl] = __builtin_bit_cast(bf16, (unsigned short)(u >> 16));
  }
  __syncthreads();
  bf16* vdst = Vt + ((size_t)(b * 16 + h) * 64) * S_TOK + s0;
#pragma unroll
  for (int j = 0; j < 2; j++) {
    int idx = tid + 256 * j;
    int d = idx >> 3, sc8 = (idx & 7) * 8;
    bf16x8 o;
#pragma unroll
    for (int m2 = 0; m2 < 8; m2++) {
      int sp = sc8 + m2;  // permuted position; invert sigma to find source s
      int ss = (sp & ~31) | ((sp >> 1) & 15) | ((sp & 1) << 4);
      o[m2] = sT[d * 72 + ss];
    }
    *(bf16x8*)(vdst + (size_t)d * S_TOK + sc8) = o;
  }
}

// ---------- fused attention v5: v4 + fully-unrolled epilogue ----------
// R3/R5 post-mortem: the epilogue's `#pragma unroll 1` loop indexed O[rt][dt]
// with a RUNTIME rt -> the whole O array was demoted to scratch for the entire
// kernel (identical 64 MB spill at both 128- and 168-reg budgets; VGPR_Count
// dropped to 56 because O wasn't in registers). Fully unrolling makes rt
// compile-time -> O register-allocated -> zero scratch.
__global__ __launch_bounds__(256, 3) void attn(const bf16* __restrict__ qkv,
                                               const bf16* __restrict__ Vt,
                                               bf16* __restrict__ vals) {
  __shared__ bf16 sP[4][2][16 * 40];   // [wave][rowtile][16 x stride40]  10.2 KB
  __shared__ float redO[4][16 * 72];   // per-wave partial O, rowtile-at-a-time, 18.4 KB
  __shared__ float redl[4][2][16];     // [wave][rowtile][row] partial row-sums, 0.5 KB

  const int tid = threadIdx.x;
  const int wv = tid >> 6, lane = tid & 63;
  const int wrow = wv >> 1, wkey = wv & 1;
  const int lrow = lane & 15, lgrp = lane >> 4;
  const int b = blockIdx.z, h = blockIdx.y;
  const int qbase = blockIdx.x * 64;

  const bf16* qp = qkv + (size_t)(b * S_TOK + qbase + wrow * 32) * E3 + h * 192;
  const bf16* kp = qkv + (size_t)(b * S_TOK) * E3 + h * 192 + 64;
  const bf16* vp = Vt + (size_t)((b * 16 + h) * 64) * S_TOK;

  // Q A-fragments hoisted to registers: A[m=lane&15][k=lgrp*8+j]
  bf16x8 qa[2][2];
#pragma unroll
  for (int rt = 0; rt < 2; rt++)
#pragma unroll
    for (int dh = 0; dh < 2; dh++)
      qa[rt][dh] = *(const bf16x8*)(qp + (size_t)(rt * 16 + lrow) * E3 + dh * 32 + lgrp * 8);

  floatx4 O[2][4] = {};
  floatx4 lacc[2] = {};
  bf16x8 ones;
  const bf16 one1 = (bf16)1.0f;
#pragma unroll
  for (int j = 0; j < 8; j++) ones[j] = one1;

  const int kt0 = wkey * (S_TOK / 32 / 2);
  for (int kt = kt0; kt < kt0 + S_TOK / 32 / 2; kt++) {
    bf16x8 kf[2][2], vf[4];
#pragma unroll
    for (int t = 0; t < 2; t++)
#pragma unroll
      for (int dh = 0; dh < 2; dh++)
        kf[t][dh] = *(const bf16x8*)(kp + (size_t)(kt * 32 + t * 16 + lrow) * E3 + dh * 32 + lgrp * 8);
#pragma unroll
    for (int dt = 0; dt < 4; dt++)
      vf[dt] = *(const bf16x8*)(vp + (size_t)(dt * 16 + lrow) * S_TOK + kt * 32 + lgrp * 8);

    // QK^T (pre-scaled), exp2, pack P to LDS in A-layout order (sigma cols 2c,2c+1)
#pragma unroll
    for (int rt = 0; rt < 2; rt++) {
      floatx4 sc0 = {0.f, 0.f, 0.f, 0.f}, sc1 = {0.f, 0.f, 0.f, 0.f};
      sc0 = MFMA16(qa[rt][0], kf[0][0], sc0);
      sc0 = MFMA16(qa[rt][1], kf[0][1], sc0);
      sc1 = MFMA16(qa[rt][0], kf[1][0], sc1);
      sc1 = MFMA16(qa[rt][1], kf[1][1], sc1);
#pragma unroll
      for (int r = 0; r < 4; r++) {
        bf16x2 h2;
        h2[0] = (bf16)EXP2(sc0[r]);
        h2[1] = (bf16)EXP2(sc1[r]);
        *(unsigned*)&sP[wv][rt][(lgrp * 4 + r) * 40 + lrow * 2] =
            __builtin_bit_cast(unsigned, h2);
      }
    }
    // P back as A-frags; PV + row-sum via ones-column MFMA
#pragma unroll
    for (int rt = 0; rt < 2; rt++) {
      bf16x8 pf = *(const bf16x8*)&sP[wv][rt][lrow * 40 + lgrp * 8];
#pragma unroll
      for (int dt = 0; dt < 4; dt++) O[rt][dt] = MFMA16(pf, vf[dt], O[rt][dt]);
      lacc[rt] = MFMA16(pf, ones, lacc[rt]);
    }
  }

  // ---- pairwise cross-wave reduction (waves 2p, 2p+1 share rows), normalize ----
  if (lrow == 0) {  // lanes 0,16,32,48 cover rows lgrp*4+r
#pragma unroll
    for (int rt = 0; rt < 2; rt++)
#pragma unroll
      for (int r = 0; r < 4; r++)
        redl[wv][rt][lgrp * 4 + r] = lacc[rt][r];
  }
  bf16* vout = vals + (size_t)(b * S_TOK + qbase) * DMODEL + h * 64;
#pragma unroll
  for (int rt = 0; rt < 2; rt++) {  // FULLY UNROLLED: rt compile-time, O stays in regs
    __syncthreads();  // prior rt's reads done (and redl visible for rt==0)
#pragma unroll
    for (int dt = 0; dt < 4; dt++)
#pragma unroll
      for (int r = 0; r < 4; r++)
        redO[wv][(lgrp * 4 + r) * 72 + dt * 16 + lrow] = O[rt][dt][r];
    __syncthreads();
    // 256 threads reduce both pairs: pair p covers q-rows p*32 + rt*16 + [0,16)
    const int p = tid >> 7, t2 = tid & 127;
    const int row = t2 >> 3, col = (t2 & 7) * 8;
    float ls = redl[2 * p][rt][row] + redl[2 * p + 1][rt][row];
    float rinv = __builtin_amdgcn_rcpf(ls);
    const float4 a0 = *(const float4*)&redO[2 * p][row * 72 + col];
    const float4 a1 = *(const float4*)&redO[2 * p][row * 72 + col + 4];
    const float4 b0 = *(const float4*)&redO[2 * p + 1][row * 72 + col];
    const float4 b1 = *(const float4*)&redO[2 * p + 1][row * 72 + col + 4];
    bf16x8 o;
    o[0] = (bf16)((a0.x + b0.x) * rinv); o[1] = (bf16)((a0.y + b0.y) * rinv);
    o[2] = (bf16)((a0.z + b0.z) * rinv); o[3] = (bf16)((a0.w + b0.w) * rinv);
    o[4] = (bf16)((a1.x + b1.x) * rinv); o[5] = (bf16)((a1.y + b1.y) * rinv);
    o[6] = (bf16)((a1.z + b1.z) * rinv); o[7] = (bf16)((a1.w + b1.w) * rinv);
    *(bf16x8*)(vout + (size_t)(p * 32 + rt * 16 + row) * DMODEL + col) = o;
  }
}

// ---------- host ----------
extern "C" void kernel_launch(void* const* d_in, const int* in_sizes, int n_in,
                              void* d_out, int out_size, void* d_ws, size_t ws_size,
                              hipStream_t stream) {
  const float* X = (const float*)d_in[0];     // (2,2048,1024)
  const float* Wqkv = (const float*)d_in[1];  // (3072,1024)
  const float* Wout = (const float*)d_in[2];  // (1024,1024)
  float* out = (float*)d_out;                 // (2,2048,1024)

  char* ws = (char*)d_ws;
  bf16* Xb = (bf16*)(ws);                          //  8 MB
  bf16* Wqb = (bf16*)(ws + ((size_t)8 << 20));     //  6 MB
  bf16* Wob = (bf16*)(ws + ((size_t)14 << 20));    //  2 MB
  bf16* qkvb = (bf16*)(ws + ((size_t)16 << 20));   // 24 MB (4096 x 3072)
  bf16* Vt = (bf16*)(ws + ((size_t)40 << 20));     //  8 MB (2*16*64 x 2048)
  bf16* vals = (bf16*)(ws + ((size_t)48 << 20));   //  8 MB (4096 x 1024)

  cvt_f32_bf16<<<4194304 / 2048, 256, 0, stream>>>(X, Xb, 4194304);
  cvt_wqkv<<<3145728 / 2048, 256, 0, stream>>>(Wqkv, Wqb, 3145728);
  cvt_f32_bf16<<<1048576 / 2048, 256, 0, stream>>>(Wout, Wob, 1048576);

  // qkv = X @ Wqkv^T : (4096,1024)x(3072,1024)^T -> (4096,3072) bf16
  gemm_bt<true><<<dim3(24, 32), 256, 0, stream>>>(Xb, Wqb, qkvb, 4096, 3072, 1024);

  transpose_v<<<dim3(32, 16, 2), 256, 0, stream>>>(qkvb, Vt);

  attn<<<dim3(32, 16, 2), 256, 0, stream>>>(qkvb, Vt, vals);

  // out = vals @ Wout^T : (4096,1024)x(1024,1024)^T -> (4096,1024) fp32
  gemm_bt<false><<<dim3(8, 32), 256, 0, stream>>>(vals, Wob, out, 4096, 1024, 1024);
}